// Round 1
// baseline (295.776 us; speedup 1.0000x reference)
//
#include <hip/hip_runtime.h>
#include <math.h>

#define BB 4
#define NN 262144
#define NPIX (BB*NN)   // 1048576
#define NI 4
#define HH 64
#define NO 3

__device__ __forceinline__ float fast_tanh(float x) {
    // tanh(x) = 1 - 2/(exp(2x)+1); saturates correctly at +-inf
    float e = __expf(2.0f * x);
    return 1.0f - __fdividef(2.0f, e + 1.0f);
}

// monotone float<->uint mapping so unsigned atomicMin/Max give float min/max
__device__ __forceinline__ unsigned f2mono(float f) {
    unsigned u = __float_as_uint(f);
    return (u & 0x80000000u) ? ~u : (u | 0x80000000u);
}
__device__ __forceinline__ float mono2f(unsigned m) {
    unsigned u = (m & 0x80000000u) ? (m & 0x7FFFFFFFu) : ~m;
    return __uint_as_float(u);
}

__global__ __launch_bounds__(256) void cppn_init(unsigned* mm) {
    mm[0] = 0xFFFFFFFFu; // running-min accumulator (mono space)
    mm[1] = 0u;          // running-max accumulator
}

__global__ __launch_bounds__(256) void cppn_main(
    const float* __restrict__ x,
    const float* __restrict__ W1, const float* __restrict__ b1,
    const float* __restrict__ W2, const float* __restrict__ b2,
    const float* __restrict__ W3, const float* __restrict__ b3,
    float* __restrict__ out, unsigned* __restrict__ mm)
{
    __shared__ float sW1[NI * HH];
    __shared__ float sb1[HH];
    __shared__ float sW2t[HH * HH];  // [k][h] = W2[h][k] (column-major: contiguous per output k)
    __shared__ float sb2[HH];
    __shared__ float sW3[HH * NO];
    __shared__ float sb3[NO];
    __shared__ float rmin[4], rmax[4];

    const int t = threadIdx.x;
    for (int i = t; i < NI * HH; i += 256) sW1[i] = W1[i];
    for (int i = t; i < HH; i += 256) { sb1[i] = b1[i]; sb2[i] = b2[i]; }
    for (int i = t; i < HH * HH; i += 256) {
        int h = i >> 6, k = i & 63;
        sW2t[k * HH + h] = W2[i];
    }
    for (int i = t; i < HH * NO; i += 256) sW3[i] = W3[i];
    if (t < NO) sb3[t] = b3[t];
    __syncthreads();

    const int p = blockIdx.x * 256 + t;
    float vmin = INFINITY, vmax = -INFINITY;

    if (p < NPIX) {
        const float4 xv = reinterpret_cast<const float4*>(x)[p];

        float h1[HH];
        #pragma unroll
        for (int h = 0; h < HH; ++h) {
            float s = sb1[h]
                    + xv.x * sW1[0 * HH + h]
                    + xv.y * sW1[1 * HH + h]
                    + xv.z * sW1[2 * HH + h]
                    + xv.w * sW1[3 * HH + h];
            h1[h] = fast_tanh(s);
        }

        float o0 = sb3[0], o1 = sb3[1], o2 = sb3[2];
        #pragma unroll 2
        for (int k = 0; k < HH; ++k) {
            const float4* wc = reinterpret_cast<const float4*>(sW2t + k * HH);
            float s0 = 0.f, s1 = 0.f, s2 = 0.f, s3 = 0.f;
            #pragma unroll
            for (int q = 0; q < HH / 4; ++q) {
                float4 w = wc[q];
                s0 += h1[4 * q + 0] * w.x;
                s1 += h1[4 * q + 1] * w.y;
                s2 += h1[4 * q + 2] * w.z;
                s3 += h1[4 * q + 3] * w.w;
            }
            float h2 = fast_tanh(((s0 + s1) + (s2 + s3)) + sb2[k]);
            o0 += h2 * sW3[k * NO + 0];
            o1 += h2 * sW3[k * NO + 1];
            o2 += h2 * sW3[k * NO + 2];
        }

        out[0 * NPIX + p] = o0;
        out[1 * NPIX + p] = o1;
        out[2 * NPIX + p] = o2;
        vmin = fminf(fminf(o0, o1), o2);
        vmax = fmaxf(fmaxf(o0, o1), o2);
    }

    // wave64 reduction
    #pragma unroll
    for (int off = 32; off > 0; off >>= 1) {
        vmin = fminf(vmin, __shfl_down(vmin, off));
        vmax = fmaxf(vmax, __shfl_down(vmax, off));
    }
    const int wid = t >> 6;
    if ((t & 63) == 0) { rmin[wid] = vmin; rmax[wid] = vmax; }
    __syncthreads();
    if (t == 0) {
        float m = fminf(fminf(rmin[0], rmin[1]), fminf(rmin[2], rmin[3]));
        float M = fmaxf(fmaxf(rmax[0], rmax[1]), fmaxf(rmax[2], rmax[3]));
        atomicMin(&mm[0], f2mono(m));
        atomicMax(&mm[1], f2mono(M));
    }
}

__global__ __launch_bounds__(256) void cppn_norm(float4* __restrict__ out,
                                                 const unsigned* __restrict__ mm)
{
    const float mn = mono2f(mm[0]);
    const float mx = mono2f(mm[1]);
    const float inv = __fdividef(1.0f, mx - mn);
    const int i = blockIdx.x * 256 + threadIdx.x;
    float4 v = out[i];
    v.x = fminf(fmaxf((v.x - mn) * inv, 0.0f), 1.0f);
    v.y = fminf(fmaxf((v.y - mn) * inv, 0.0f), 1.0f);
    v.z = fminf(fmaxf((v.z - mn) * inv, 0.0f), 1.0f);
    v.w = fminf(fmaxf((v.w - mn) * inv, 0.0f), 1.0f);
    out[i] = v;
}

extern "C" void kernel_launch(void* const* d_in, const int* in_sizes, int n_in,
                              void* d_out, int out_size, void* d_ws, size_t ws_size,
                              hipStream_t stream) {
    const float* x  = (const float*)d_in[0];
    const float* W1 = (const float*)d_in[1];
    const float* b1 = (const float*)d_in[2];
    const float* W2 = (const float*)d_in[3];
    const float* b2 = (const float*)d_in[4];
    const float* W3 = (const float*)d_in[5];
    const float* b3 = (const float*)d_in[6];
    float* out = (float*)d_out;
    unsigned* mm = (unsigned*)d_ws;

    cppn_init<<<1, 256, 0, stream>>>(mm);
    cppn_main<<<NPIX / 256, 256, 0, stream>>>(x, W1, b1, W2, b2, W3, b3, out, mm);
    // NPIX*NO floats = 786432 float4 elements; 256 threads/block
    cppn_norm<<<(NPIX * NO / 4) / 256, 256, 0, stream>>>((float4*)out, mm);
}

// Round 2
// 104.705 us; speedup vs baseline: 2.8248x; 2.8248x over previous
//
#include <hip/hip_runtime.h>
#include <math.h>

#define NPIX 1048576
#define HH 64
#define NO 3
#define NBLK 2048
#define ITER 8   // NBLK * 4 waves * ITER * 16 px = 1048576

typedef float f32x4 __attribute__((ext_vector_type(4)));
typedef __bf16 bf16x8 __attribute__((ext_vector_type(8)));

union BF8 { unsigned short u[8]; bf16x8 v; };

#define MFMA16(a, b, c) __builtin_amdgcn_mfma_f32_16x16x32_bf16((a), (b), (c), 0, 0, 0)

__device__ __forceinline__ unsigned short f2bf(float f) {
    unsigned u = __float_as_uint(f);
    return (unsigned short)((u + 0x7FFFu + ((u >> 16) & 1u)) >> 16);  // RNE
}
__device__ __forceinline__ float fast_tanh(float x) {
    float e = __expf(2.0f * x);
    return 1.0f - __fdividef(2.0f, e + 1.0f);
}
__device__ __forceinline__ unsigned f2mono(float f) {
    unsigned u = __float_as_uint(f);
    return (u & 0x80000000u) ? ~u : (u | 0x80000000u);
}
__device__ __forceinline__ float mono2f(unsigned m) {
    unsigned u = (m & 0x80000000u) ? (m & 0x7FFFFFFFu) : ~m;
    return __uint_as_float(u);
}
// byte-address XOR swizzle: spread 128B-stride rows across 16B slots (G4)
__device__ __forceinline__ int swz(int a, int row) { return a ^ ((row & 7) << 4); }

__global__ __launch_bounds__(256) void cppn_init(unsigned* mm) {
    mm[0] = 0xFFFFFFFFu;
    mm[1] = 0u;
}

__global__ __launch_bounds__(256, 4) void cppn_main(
    const float* __restrict__ x,
    const float* __restrict__ W1, const float* __restrict__ b1,
    const float* __restrict__ W2, const float* __restrict__ b2,
    const float* __restrict__ W3, const float* __restrict__ b3,
    float* __restrict__ out, unsigned* __restrict__ mm)
{
    // per-wave activation buffers: [wave][h1|h2][16 px rows * 64 bf16]
    __shared__ unsigned short sh[4][2][1024];
    __shared__ float rmin[4], rmax[4];

    const int t = threadIdx.x;
    const int w = t >> 6;        // wave id
    const int l = t & 63;        // lane
    const int g = l >> 4;        // k-group (0..3)
    const int q = l & 15;        // row/col index within fragment

    // ---- A fragments (transposed weights), built once per block ----
    // L1: A[row=h][k] = W1aug[k][h]; k<4 -> W1, k==4 -> b1 (bias fold), else 0
    bf16x8 A1[4];
    #pragma unroll
    for (int m = 0; m < 4; ++m) {
        BF8 tmp;
        #pragma unroll
        for (int j = 0; j < 8; ++j) {
            const int k = g * 8 + j;
            float v = 0.0f;
            if (k < 4) v = W1[k * HH + m * 16 + q];
            else if (k == 4) v = b1[m * 16 + q];
            tmp.u[j] = f2bf(v);
        }
        A1[m] = tmp.v;
    }
    // L2: A[row=h2][k=h1] = W2[h1][h2]
    bf16x8 A2[2][4];
    #pragma unroll
    for (int s = 0; s < 2; ++s)
        #pragma unroll
        for (int m = 0; m < 4; ++m) {
            BF8 tmp;
            #pragma unroll
            for (int j = 0; j < 8; ++j)
                tmp.u[j] = f2bf(W2[(s * 32 + g * 8 + j) * HH + m * 16 + q]);
            A2[s][m] = tmp.v;
        }
    // L3: A[row=o][k=h2] = W3[h2][o], rows 3..15 zero
    bf16x8 A3[2];
    #pragma unroll
    for (int s = 0; s < 2; ++s) {
        BF8 tmp;
        #pragma unroll
        for (int j = 0; j < 8; ++j)
            tmp.u[j] = (q < NO) ? f2bf(W3[(s * 32 + g * 8 + j) * NO + q]) : (unsigned short)0;
        A3[s] = tmp.v;
    }
    // per-lane L2 bias slice: b2[m*16 + g*4 + r]
    float b2l[16];
    #pragma unroll
    for (int m = 0; m < 4; ++m)
        #pragma unroll
        for (int r = 0; r < 4; ++r)
            b2l[m * 4 + r] = b2[m * 16 + g * 4 + r];
    const float b30 = b3[0], b31 = b3[1], b32 = b3[2];

    char* const h1b = (char*)&sh[w][0][0];
    char* const h2b = (char*)&sh[w][1][0];
    const f32x4 z = {0.0f, 0.0f, 0.0f, 0.0f};
    float vmin = INFINITY, vmax = -INFINITY;

    for (int it = 0; it < ITER; ++it) {
        const int px0 = ((blockIdx.x * 4 + w) * ITER + it) * 16;
        const int pxg = px0 + q;

        // B1 frag: xaug^T[k][px]; only k<8 lanes (g==0) carry data {x0..x3, 1}
        const float4 xv = reinterpret_cast<const float4*>(x)[pxg];
        BF8 bx;
        #pragma unroll
        for (int j = 0; j < 8; ++j) bx.u[j] = 0;
        if (g == 0) {
            bx.u[0] = f2bf(xv.x); bx.u[1] = f2bf(xv.y);
            bx.u[2] = f2bf(xv.z); bx.u[3] = f2bf(xv.w);
            bx.u[4] = 0x3F80;  // 1.0bf16 (bias lane)
        }

        // ---- layer 1: h1^T[h][px] ----
        f32x4 c1[4];
        #pragma unroll
        for (int m = 0; m < 4; ++m) c1[m] = MFMA16(A1[m], bx.v, z);

        #pragma unroll
        for (int m = 0; m < 4; ++m) {
            const unsigned p0 = f2bf(fast_tanh(c1[m][0]));
            const unsigned p1 = f2bf(fast_tanh(c1[m][1]));
            const unsigned p2 = f2bf(fast_tanh(c1[m][2]));
            const unsigned p3 = f2bf(fast_tanh(c1[m][3]));
            uint2 pk; pk.x = p0 | (p1 << 16); pk.y = p2 | (p3 << 16);
            *(uint2*)(h1b + swz(q * 128 + (m * 16 + g * 4) * 2, q)) = pk;
        }
        asm volatile("s_waitcnt lgkmcnt(0)" ::: "memory");
        __builtin_amdgcn_sched_barrier(0);

        // ---- layer 2: B frag = h1^T[k][px] ----
        bf16x8 Bf0 = *(const bf16x8*)(h1b + swz(q * 128 + 0 * 64 + g * 16, q));
        bf16x8 Bf1 = *(const bf16x8*)(h1b + swz(q * 128 + 1 * 64 + g * 16, q));
        f32x4 c2[4];
        #pragma unroll
        for (int m = 0; m < 4; ++m) {
            c2[m] = MFMA16(A2[0][m], Bf0, z);
            c2[m] = MFMA16(A2[1][m], Bf1, c2[m]);
        }
        #pragma unroll
        for (int m = 0; m < 4; ++m) {
            const unsigned p0 = f2bf(fast_tanh(c2[m][0] + b2l[m * 4 + 0]));
            const unsigned p1 = f2bf(fast_tanh(c2[m][1] + b2l[m * 4 + 1]));
            const unsigned p2 = f2bf(fast_tanh(c2[m][2] + b2l[m * 4 + 2]));
            const unsigned p3 = f2bf(fast_tanh(c2[m][3] + b2l[m * 4 + 3]));
            uint2 pk; pk.x = p0 | (p1 << 16); pk.y = p2 | (p3 << 16);
            *(uint2*)(h2b + swz(q * 128 + (m * 16 + g * 4) * 2, q)) = pk;
        }
        asm volatile("s_waitcnt lgkmcnt(0)" ::: "memory");
        __builtin_amdgcn_sched_barrier(0);

        // ---- layer 3: out^T[o][px] ----
        bf16x8 Bg0 = *(const bf16x8*)(h2b + swz(q * 128 + 0 * 64 + g * 16, q));
        bf16x8 Bg1 = *(const bf16x8*)(h2b + swz(q * 128 + 1 * 64 + g * 16, q));
        f32x4 c3 = MFMA16(A3[0], Bg0, z);
        c3 = MFMA16(A3[1], Bg1, c3);

        if (g == 0) {
            const float o0 = c3[0] + b30;
            const float o1 = c3[1] + b31;
            const float o2 = c3[2] + b32;
            out[0 * NPIX + pxg] = o0;
            out[1 * NPIX + pxg] = o1;
            out[2 * NPIX + pxg] = o2;
            vmin = fminf(vmin, fminf(fminf(o0, o1), o2));
            vmax = fmaxf(vmax, fmaxf(fmaxf(o0, o1), o2));
        }
    }

    // wave64 then block min/max reduction
    #pragma unroll
    for (int off = 32; off > 0; off >>= 1) {
        vmin = fminf(vmin, __shfl_down(vmin, off));
        vmax = fmaxf(vmax, __shfl_down(vmax, off));
    }
    if (l == 0) { rmin[w] = vmin; rmax[w] = vmax; }
    __syncthreads();
    if (t == 0) {
        float m = fminf(fminf(rmin[0], rmin[1]), fminf(rmin[2], rmin[3]));
        float M = fmaxf(fmaxf(rmax[0], rmax[1]), fmaxf(rmax[2], rmax[3]));
        atomicMin(&mm[0], f2mono(m));
        atomicMax(&mm[1], f2mono(M));
    }
}

__global__ __launch_bounds__(256) void cppn_norm(float4* __restrict__ out,
                                                 const unsigned* __restrict__ mm)
{
    const float mn = mono2f(mm[0]);
    const float mx = mono2f(mm[1]);
    const float inv = __fdividef(1.0f, mx - mn);
    const int i = blockIdx.x * 256 + threadIdx.x;
    float4 v = out[i];
    v.x = fminf(fmaxf((v.x - mn) * inv, 0.0f), 1.0f);
    v.y = fminf(fmaxf((v.y - mn) * inv, 0.0f), 1.0f);
    v.z = fminf(fmaxf((v.z - mn) * inv, 0.0f), 1.0f);
    v.w = fminf(fmaxf((v.w - mn) * inv, 0.0f), 1.0f);
    out[i] = v;
}

extern "C" void kernel_launch(void* const* d_in, const int* in_sizes, int n_in,
                              void* d_out, int out_size, void* d_ws, size_t ws_size,
                              hipStream_t stream) {
    const float* x  = (const float*)d_in[0];
    const float* W1 = (const float*)d_in[1];
    const float* b1 = (const float*)d_in[2];
    const float* W2 = (const float*)d_in[3];
    const float* b2 = (const float*)d_in[4];
    const float* W3 = (const float*)d_in[5];
    const float* b3 = (const float*)d_in[6];
    float* out = (float*)d_out;
    unsigned* mm = (unsigned*)d_ws;

    cppn_init<<<1, 256, 0, stream>>>(mm);
    cppn_main<<<NBLK, 256, 0, stream>>>(x, W1, b1, W2, b2, W3, b3, out, mm);
    cppn_norm<<<(NPIX * NO / 4) / 256, 256, 0, stream>>>((float4*)out, mm);
}

// Round 3
// 75.704 us; speedup vs baseline: 3.9070x; 1.3831x over previous
//
#include <hip/hip_runtime.h>
#include <math.h>

#define NPIX 1048576
#define HH 64
#define NO 3
#define NBLK 2048
#define ITER 8     // NBLK * 4 waves * ITER * 16 px = 1048576
#define K2C 2.8853900817779268f  // 2*log2(e)

typedef float f32x4 __attribute__((ext_vector_type(4)));
typedef __bf16 bf16x8 __attribute__((ext_vector_type(8)));
typedef __bf16 bf16x2 __attribute__((ext_vector_type(2)));

union BF8 { __bf16 h[8]; bf16x8 v; uint4 u4; };
union PK2 { bf16x2 h; unsigned u; };
union F4U { float f[4]; uint4 u; };

#define MFMA16(a, b, c) __builtin_amdgcn_mfma_f32_16x16x32_bf16((a), (b), (c), 0, 0, 0)

// t is pre-scaled: t = 2*log2e*x (+ folded bias). tanh(x) = 1 - 2/(exp2(t)+1)
__device__ __forceinline__ float tanh_t(float t) {
    float e = __builtin_amdgcn_exp2f(t);
    float r = __builtin_amdgcn_rcpf(e + 1.0f);
    return fmaf(-2.0f, r, 1.0f);   // saturates correctly: t->+inf => 1, t->-inf => -1
}
__device__ __forceinline__ unsigned f2mono(float f) {
    unsigned u = __float_as_uint(f);
    return (u & 0x80000000u) ? ~u : (u | 0x80000000u);
}
__device__ __forceinline__ float mono2f(unsigned m) {
    unsigned u = (m & 0x80000000u) ? (m & 0x7FFFFFFFu) : ~m;
    return __uint_as_float(u);
}
// byte-address XOR swizzle (G4), identical to R1 (verified)
__device__ __forceinline__ int swz(int a, int row) { return a ^ ((row & 7) << 4); }

// ---- one-wave pre-pack: build per-lane MFMA A-fragments + scaled b2 into ws ----
// layout per lane (18 uint4): [0..3]=A1, [4..11]=A2[s][m] at 4+s*4+m, [12..13]=A3, [14..17]=K2*b2 slice
__global__ __launch_bounds__(64) void cppn_pack(
    const float* __restrict__ W1, const float* __restrict__ b1,
    const float* __restrict__ W2, const float* __restrict__ b2,
    const float* __restrict__ W3, const float* __restrict__ b3,
    unsigned* __restrict__ mm, uint4* __restrict__ fr)
{
    const int l = threadIdx.x, g = l >> 4, q = l & 15;
    if (l == 0) { mm[0] = 0xFFFFFFFFu; mm[1] = 0u; }
    uint4* o = fr + l * 18;

    // L1: A[row=h][k] = W1aug[k][h]; k<4 -> W1, k==4 -> b1 (bias fold), else 0
    #pragma unroll
    for (int m = 0; m < 4; ++m) {
        BF8 t;
        #pragma unroll
        for (int j = 0; j < 8; ++j) {
            const int k = g * 8 + j;
            float v = 0.0f;
            if (k < 4) v = W1[k * HH + m * 16 + q];
            else if (k == 4) v = b1[m * 16 + q];
            t.h[j] = (__bf16)v;
        }
        o[m] = t.u4;
    }
    // L2: A[row=h2][k=h1] = W2[h1][h2]
    #pragma unroll
    for (int s = 0; s < 2; ++s)
        #pragma unroll
        for (int m = 0; m < 4; ++m) {
            BF8 t;
            #pragma unroll
            for (int j = 0; j < 8; ++j)
                t.h[j] = (__bf16)W2[(s * 32 + g * 8 + j) * HH + m * 16 + q];
            o[4 + s * 4 + m] = t.u4;
        }
    // L3: A[row=o][k=h2] = W3[h2][o], rows 3..15 zero
    #pragma unroll
    for (int s = 0; s < 2; ++s) {
        BF8 t;
        #pragma unroll
        for (int j = 0; j < 8; ++j)
            t.h[j] = (q < NO) ? (__bf16)W3[(s * 32 + g * 8 + j) * NO + q] : (__bf16)0.0f;
        o[12 + s] = t.u4;
    }
    // pre-scaled L2 bias slice: K2 * b2[m*16 + g*4 + r]
    #pragma unroll
    for (int m = 0; m < 4; ++m) {
        F4U t;
        #pragma unroll
        for (int r = 0; r < 4; ++r) t.f[r] = K2C * b2[m * 16 + g * 4 + r];
        o[14 + m] = t.u;
    }
}

__global__ __launch_bounds__(256, 4) void cppn_main(
    const float* __restrict__ x,
    const float* __restrict__ b3,
    const uint4* __restrict__ fr,
    float* __restrict__ out, unsigned* __restrict__ mm)
{
    __shared__ unsigned short sh[4][2][1024];
    __shared__ float rmin[4], rmax[4];

    const int t = threadIdx.x;
    const int w = t >> 6;
    const int l = t & 63;
    const int g = l >> 4;
    const int q = l & 15;

    // ---- load prebuilt fragments (18 dwordx4, L2-hit) ----
    const uint4* fo = fr + l * 18;
    bf16x8 A1[4], A2[2][4], A3[2];
    #pragma unroll
    for (int m = 0; m < 4; ++m) { BF8 u; u.u4 = fo[m]; A1[m] = u.v; }
    #pragma unroll
    for (int s = 0; s < 2; ++s)
        #pragma unroll
        for (int m = 0; m < 4; ++m) { BF8 u; u.u4 = fo[4 + s * 4 + m]; A2[s][m] = u.v; }
    #pragma unroll
    for (int s = 0; s < 2; ++s) { BF8 u; u.u4 = fo[12 + s]; A3[s] = u.v; }
    float Kb[16];
    #pragma unroll
    for (int m = 0; m < 4; ++m) {
        F4U u; u.u = fo[14 + m];
        #pragma unroll
        for (int r = 0; r < 4; ++r) Kb[m * 4 + r] = u.f[r];
    }
    const float b30 = b3[0], b31 = b3[1], b32 = b3[2];

    // loop-invariant LDS byte offsets
    char* const h1b = (char*)&sh[w][0][0];
    char* const h2b = (char*)&sh[w][1][0];
    int wa[4];
    #pragma unroll
    for (int m = 0; m < 4; ++m) wa[m] = swz(q * 128 + (m * 16 + g * 4) * 2, q);
    const int ra0 = swz(q * 128 + g * 16, q);
    const int ra1 = swz(q * 128 + 64 + g * 16, q);

    const f32x4 z = {0.0f, 0.0f, 0.0f, 0.0f};
    float vmin = INFINITY, vmax = -INFINITY;

    for (int it = 0; it < ITER; ++it) {
        const int pxg = ((blockIdx.x * 4 + w) * ITER + it) * 16 + q;

        // B1 frag: xaug^T[k][px]; only g==0 lanes carry {x0..x3, 1}
        const float4 xv = reinterpret_cast<const float4*>(x)[pxg];
        BF8 bx;
        bx.u4 = uint4{0, 0, 0, 0};
        if (g == 0) {
            PK2 p01, p23;
            p01.h = bf16x2{(__bf16)xv.x, (__bf16)xv.y};
            p23.h = bf16x2{(__bf16)xv.z, (__bf16)xv.w};
            bx.u4.x = p01.u;
            bx.u4.y = p23.u;
            bx.u4.z = 0x3F80u;  // {1.0bf16, 0} bias lane k=4
        }

        // ---- layer 1 ----
        f32x4 c1[4];
        #pragma unroll
        for (int m = 0; m < 4; ++m) c1[m] = MFMA16(A1[m], bx.v, z);
        #pragma unroll
        for (int m = 0; m < 4; ++m) {
            const float t0 = tanh_t(c1[m][0] * K2C);
            const float t1 = tanh_t(c1[m][1] * K2C);
            const float t2 = tanh_t(c1[m][2] * K2C);
            const float t3 = tanh_t(c1[m][3] * K2C);
            PK2 lo, hi;
            lo.h = bf16x2{(__bf16)t0, (__bf16)t1};
            hi.h = bf16x2{(__bf16)t2, (__bf16)t3};
            *(uint2*)(h1b + wa[m]) = uint2{lo.u, hi.u};
        }
        asm volatile("s_waitcnt lgkmcnt(0)" ::: "memory");
        __builtin_amdgcn_sched_barrier(0);

        // ---- layer 2 ----
        bf16x8 Bf0 = *(const bf16x8*)(h1b + ra0);
        bf16x8 Bf1 = *(const bf16x8*)(h1b + ra1);
        f32x4 c2[4];
        #pragma unroll
        for (int m = 0; m < 4; ++m) {
            c2[m] = MFMA16(A2[0][m], Bf0, z);
            c2[m] = MFMA16(A2[1][m], Bf1, c2[m]);
        }
        #pragma unroll
        for (int m = 0; m < 4; ++m) {
            const float t0 = tanh_t(fmaf(c2[m][0], K2C, Kb[m * 4 + 0]));
            const float t1 = tanh_t(fmaf(c2[m][1], K2C, Kb[m * 4 + 1]));
            const float t2 = tanh_t(fmaf(c2[m][2], K2C, Kb[m * 4 + 2]));
            const float t3 = tanh_t(fmaf(c2[m][3], K2C, Kb[m * 4 + 3]));
            PK2 lo, hi;
            lo.h = bf16x2{(__bf16)t0, (__bf16)t1};
            hi.h = bf16x2{(__bf16)t2, (__bf16)t3};
            *(uint2*)(h2b + wa[m]) = uint2{lo.u, hi.u};
        }
        asm volatile("s_waitcnt lgkmcnt(0)" ::: "memory");
        __builtin_amdgcn_sched_barrier(0);

        // ---- layer 3 ----
        bf16x8 Bg0 = *(const bf16x8*)(h2b + ra0);
        bf16x8 Bg1 = *(const bf16x8*)(h2b + ra1);
        f32x4 c3 = MFMA16(A3[0], Bg0, z);
        c3 = MFMA16(A3[1], Bg1, c3);

        if (g == 0) {
            const float o0 = c3[0] + b30;
            const float o1 = c3[1] + b31;
            const float o2 = c3[2] + b32;
            out[0 * NPIX + pxg] = o0;
            out[1 * NPIX + pxg] = o1;
            out[2 * NPIX + pxg] = o2;
            vmin = fminf(vmin, fminf(fminf(o0, o1), o2));
            vmax = fmaxf(vmax, fmaxf(fmaxf(o0, o1), o2));
        }
    }

    #pragma unroll
    for (int off = 32; off > 0; off >>= 1) {
        vmin = fminf(vmin, __shfl_down(vmin, off));
        vmax = fmaxf(vmax, __shfl_down(vmax, off));
    }
    if (l == 0) { rmin[w] = vmin; rmax[w] = vmax; }
    __syncthreads();
    if (t == 0) {
        float m = fminf(fminf(rmin[0], rmin[1]), fminf(rmin[2], rmin[3]));
        float M = fmaxf(fmaxf(rmax[0], rmax[1]), fmaxf(rmax[2], rmax[3]));
        atomicMin(&mm[0], f2mono(m));
        atomicMax(&mm[1], f2mono(M));
    }
}

__global__ __launch_bounds__(256) void cppn_norm(float4* __restrict__ out,
                                                 const unsigned* __restrict__ mm)
{
    const float mn = mono2f(mm[0]);
    const float mx = mono2f(mm[1]);
    const float inv = __fdividef(1.0f, mx - mn);
    const int i = blockIdx.x * 256 + threadIdx.x;
    float4 v = out[i];
    v.x = fminf(fmaxf((v.x - mn) * inv, 0.0f), 1.0f);
    v.y = fminf(fmaxf((v.y - mn) * inv, 0.0f), 1.0f);
    v.z = fminf(fmaxf((v.z - mn) * inv, 0.0f), 1.0f);
    v.w = fminf(fmaxf((v.w - mn) * inv, 0.0f), 1.0f);
    out[i] = v;
}

extern "C" void kernel_launch(void* const* d_in, const int* in_sizes, int n_in,
                              void* d_out, int out_size, void* d_ws, size_t ws_size,
                              hipStream_t stream) {
    const float* x  = (const float*)d_in[0];
    const float* W1 = (const float*)d_in[1];
    const float* b1 = (const float*)d_in[2];
    const float* W2 = (const float*)d_in[3];
    const float* b2 = (const float*)d_in[4];
    const float* W3 = (const float*)d_in[5];
    const float* b3 = (const float*)d_in[6];
    float* out = (float*)d_out;
    unsigned* mm = (unsigned*)d_ws;
    uint4* fr = (uint4*)((char*)d_ws + 256);  // 64 lanes * 18 uint4 = 18 KB

    cppn_pack<<<1, 64, 0, stream>>>(W1, b1, W2, b2, W3, b3, mm, fr);
    cppn_main<<<NBLK, 256, 0, stream>>>(x, b3, fr, out, mm);
    cppn_norm<<<(NPIX * NO / 4) / 256, 256, 0, stream>>>((float4*)out, mm);
}

// Round 4
// 74.724 us; speedup vs baseline: 3.9582x; 1.0131x over previous
//
#include <hip/hip_runtime.h>
#include <math.h>

#define NPIX 1048576
#define HH 64
#define NO 3
#define NBLK 2048
#define ITER 8     // NBLK * 4 waves * ITER * 16 px = 1048576
#define K2C 2.8853900817779268f  // 2*log2(e)

typedef float f32x4 __attribute__((ext_vector_type(4)));
typedef __bf16 bf16x8 __attribute__((ext_vector_type(8)));
typedef __bf16 bf16x2 __attribute__((ext_vector_type(2)));

union BF8 { __bf16 h[8]; bf16x8 v; uint4 u4; };
union PK2 { bf16x2 h; unsigned u; };
union F4U { float f[4]; uint4 u; };

#define MFMA16(a, b, c) __builtin_amdgcn_mfma_f32_16x16x32_bf16((a), (b), (c), 0, 0, 0)

// t pre-scaled: t = 2*log2e*x (+ folded bias). tanh(x) = 1 - 2/(exp2(t)+1)
__device__ __forceinline__ float tanh_t(float t) {
    float e = __builtin_amdgcn_exp2f(t);
    float r = __builtin_amdgcn_rcpf(e + 1.0f);
    return fmaf(-2.0f, r, 1.0f);
}
__device__ __forceinline__ unsigned f2mono(float f) {
    unsigned u = __float_as_uint(f);
    return (u & 0x80000000u) ? ~u : (u | 0x80000000u);
}
__device__ __forceinline__ float mono2f(unsigned m) {
    unsigned u = (m & 0x80000000u) ? (m & 0x7FFFFFFFu) : ~m;
    return __uint_as_float(u);
}

// k-slot -> physical h index permutation: lane (G,q) holds C rows {16m+4G+r}
// and owns B-frag k-slots {8G+j} (Bf0) and {32+8G+j} (Bf1). Bijection:
__device__ __forceinline__ int hsel(int k) {
    const int G = (k & 31) >> 3, j = k & 7;
    return ((k >= 32) ? 32 : 0) + ((j >= 4) ? 16 : 0) + 4 * G + (j & 3);
}

// ---- one-wave pre-pack: per-lane MFMA A-fragments (k-permuted) + scaled b2 ----
// layout per lane (18 uint4): [0..3]=A1, [4..11]=A2[s][m], [12..13]=A3, [14..17]=K2*b2
__global__ __launch_bounds__(64) void cppn_pack(
    const float* __restrict__ W1, const float* __restrict__ b1,
    const float* __restrict__ W2, const float* __restrict__ b2,
    const float* __restrict__ W3, const float* __restrict__ b3,
    unsigned* __restrict__ mm, uint4* __restrict__ fr)
{
    const int l = threadIdx.x, g = l >> 4, q = l & 15;
    if (l == 0) { mm[0] = 0xFFFFFFFFu; mm[1] = 0u; }
    uint4* o = fr + l * 18;

    // L1: A[row=h][k] = W1aug[k][h]; k<4 -> W1, k==4 -> b1 (bias fold). Natural k.
    #pragma unroll
    for (int m = 0; m < 4; ++m) {
        BF8 t;
        #pragma unroll
        for (int j = 0; j < 8; ++j) {
            const int k = g * 8 + j;
            float v = 0.0f;
            if (k < 4) v = W1[k * HH + m * 16 + q];
            else if (k == 4) v = b1[m * 16 + q];
            t.h[j] = (__bf16)v;
        }
        o[m] = t.u4;
    }
    // L2: A[row=h2][k] = W2[hsel(k)][h2]  (k-permuted so B comes free from C1 regs)
    #pragma unroll
    for (int s = 0; s < 2; ++s)
        #pragma unroll
        for (int m = 0; m < 4; ++m) {
            BF8 t;
            #pragma unroll
            for (int j = 0; j < 8; ++j)
                t.h[j] = (__bf16)W2[hsel(s * 32 + g * 8 + j) * HH + m * 16 + q];
            o[4 + s * 4 + m] = t.u4;
        }
    // L3: A[row=o][k] = W3[hsel(k)][o], rows 3..15 zero
    #pragma unroll
    for (int s = 0; s < 2; ++s) {
        BF8 t;
        #pragma unroll
        for (int j = 0; j < 8; ++j)
            t.h[j] = (q < NO) ? (__bf16)W3[hsel(s * 32 + g * 8 + j) * NO + q] : (__bf16)0.0f;
        o[12 + s] = t.u4;
    }
    // pre-scaled L2 bias slice: K2 * b2[m*16 + g*4 + r]
    #pragma unroll
    for (int m = 0; m < 4; ++m) {
        F4U t;
        #pragma unroll
        for (int r = 0; r < 4; ++r) t.f[r] = K2C * b2[m * 16 + g * 4 + r];
        o[14 + m] = t.u;
    }
}

__global__ __launch_bounds__(256) void cppn_main(
    const float* __restrict__ x,
    const float* __restrict__ b3,
    const uint4* __restrict__ fr,
    float* __restrict__ out, unsigned* __restrict__ mm)
{
    __shared__ float rmin[4], rmax[4];

    const int t = threadIdx.x;
    const int w = t >> 6;
    const int l = t & 63;
    const int g = l >> 4;
    const int q = l & 15;

    // ---- load prebuilt fragments (18 dwordx4, L2-hit) ----
    const uint4* fo = fr + l * 18;
    bf16x8 A1[4], A2[2][4], A3[2];
    #pragma unroll
    for (int m = 0; m < 4; ++m) { BF8 u; u.u4 = fo[m]; A1[m] = u.v; }
    #pragma unroll
    for (int s = 0; s < 2; ++s)
        #pragma unroll
        for (int m = 0; m < 4; ++m) { BF8 u; u.u4 = fo[4 + s * 4 + m]; A2[s][m] = u.v; }
    #pragma unroll
    for (int s = 0; s < 2; ++s) { BF8 u; u.u4 = fo[12 + s]; A3[s] = u.v; }
    float Kb[16];
    #pragma unroll
    for (int m = 0; m < 4; ++m) {
        F4U u; u.u = fo[14 + m];
        #pragma unroll
        for (int r = 0; r < 4; ++r) Kb[m * 4 + r] = u.f[r];
    }
    const float b30 = b3[0], b31 = b3[1], b32 = b3[2];

    const f32x4 z = {0.0f, 0.0f, 0.0f, 0.0f};
    float vmin = INFINITY, vmax = -INFINITY;

    #pragma unroll 2
    for (int it = 0; it < ITER; ++it) {
        const int pxg = ((blockIdx.x * 4 + w) * ITER + it) * 16 + q;

        // B1 frag: xaug^T[k][px]; only g==0 lanes carry {x0..x3, 1}
        const float4 xv = reinterpret_cast<const float4*>(x)[pxg];
        BF8 bx;
        bx.u4 = uint4{0, 0, 0, 0};
        if (g == 0) {
            PK2 p01, p23;
            p01.h = bf16x2{(__bf16)xv.x, (__bf16)xv.y};
            p23.h = bf16x2{(__bf16)xv.z, (__bf16)xv.w};
            bx.u4.x = p01.u;
            bx.u4.y = p23.u;
            bx.u4.z = 0x3F80u;  // {1.0bf16, 0} bias lane k=4
        }

        // ---- layer 1 ----
        f32x4 c1[4];
        #pragma unroll
        for (int m = 0; m < 4; ++m) c1[m] = MFMA16(A1[m], bx.v, z);

        // tanh + pack; B-frags assembled straight from accumulator dwords
        unsigned pkx[4], pky[4];
        #pragma unroll
        for (int m = 0; m < 4; ++m) {
            const float t0 = tanh_t(c1[m][0] * K2C);
            const float t1 = tanh_t(c1[m][1] * K2C);
            const float t2 = tanh_t(c1[m][2] * K2C);
            const float t3 = tanh_t(c1[m][3] * K2C);
            PK2 lo, hi;
            lo.h = bf16x2{(__bf16)t0, (__bf16)t1};
            hi.h = bf16x2{(__bf16)t2, (__bf16)t3};
            pkx[m] = lo.u; pky[m] = hi.u;
        }
        BF8 Bf0, Bf1;
        Bf0.u4 = uint4{pkx[0], pky[0], pkx[1], pky[1]};
        Bf1.u4 = uint4{pkx[2], pky[2], pkx[3], pky[3]};

        // ---- layer 2 ----
        f32x4 c2[4];
        #pragma unroll
        for (int m = 0; m < 4; ++m) {
            c2[m] = MFMA16(A2[0][m], Bf0.v, z);
            c2[m] = MFMA16(A2[1][m], Bf1.v, c2[m]);
        }
        #pragma unroll
        for (int m = 0; m < 4; ++m) {
            const float t0 = tanh_t(fmaf(c2[m][0], K2C, Kb[m * 4 + 0]));
            const float t1 = tanh_t(fmaf(c2[m][1], K2C, Kb[m * 4 + 1]));
            const float t2 = tanh_t(fmaf(c2[m][2], K2C, Kb[m * 4 + 2]));
            const float t3 = tanh_t(fmaf(c2[m][3], K2C, Kb[m * 4 + 3]));
            PK2 lo, hi;
            lo.h = bf16x2{(__bf16)t0, (__bf16)t1};
            hi.h = bf16x2{(__bf16)t2, (__bf16)t3};
            pkx[m] = lo.u; pky[m] = hi.u;
        }
        BF8 Bg0, Bg1;
        Bg0.u4 = uint4{pkx[0], pky[0], pkx[1], pky[1]};
        Bg1.u4 = uint4{pkx[2], pky[2], pkx[3], pky[3]};

        // ---- layer 3 ----
        f32x4 c3 = MFMA16(A3[0], Bg0.v, z);
        c3 = MFMA16(A3[1], Bg1.v, c3);

        if (g == 0) {
            const float o0 = c3[0] + b30;
            const float o1 = c3[1] + b31;
            const float o2 = c3[2] + b32;
            out[0 * NPIX + pxg] = o0;
            out[1 * NPIX + pxg] = o1;
            out[2 * NPIX + pxg] = o2;
            vmin = fminf(vmin, fminf(fminf(o0, o1), o2));
            vmax = fmaxf(vmax, fmaxf(fmaxf(o0, o1), o2));
        }
    }

    #pragma unroll
    for (int off = 32; off > 0; off >>= 1) {
        vmin = fminf(vmin, __shfl_down(vmin, off));
        vmax = fmaxf(vmax, __shfl_down(vmax, off));
    }
    if (l == 0) { rmin[w] = vmin; rmax[w] = vmax; }
    __syncthreads();
    if (t == 0) {
        float m = fminf(fminf(rmin[0], rmin[1]), fminf(rmin[2], rmin[3]));
        float M = fmaxf(fmaxf(rmax[0], rmax[1]), fmaxf(rmax[2], rmax[3]));
        atomicMin(&mm[0], f2mono(m));
        atomicMax(&mm[1], f2mono(M));
    }
}

__global__ __launch_bounds__(256) void cppn_norm(float4* __restrict__ out,
                                                 const unsigned* __restrict__ mm)
{
    const float mn = mono2f(mm[0]);
    const float mx = mono2f(mm[1]);
    const float inv = __fdividef(1.0f, mx - mn);
    const int i = blockIdx.x * 256 + threadIdx.x;
    float4 v = out[i];
    v.x = fminf(fmaxf((v.x - mn) * inv, 0.0f), 1.0f);
    v.y = fminf(fmaxf((v.y - mn) * inv, 0.0f), 1.0f);
    v.z = fminf(fmaxf((v.z - mn) * inv, 0.0f), 1.0f);
    v.w = fminf(fmaxf((v.w - mn) * inv, 0.0f), 1.0f);
    out[i] = v;
}

extern "C" void kernel_launch(void* const* d_in, const int* in_sizes, int n_in,
                              void* d_out, int out_size, void* d_ws, size_t ws_size,
                              hipStream_t stream) {
    const float* x  = (const float*)d_in[0];
    const float* W1 = (const float*)d_in[1];
    const float* b1 = (const float*)d_in[2];
    const float* W2 = (const float*)d_in[3];
    const float* b2 = (const float*)d_in[4];
    const float* W3 = (const float*)d_in[5];
    const float* b3 = (const float*)d_in[6];
    float* out = (float*)d_out;
    unsigned* mm = (unsigned*)d_ws;
    uint4* fr = (uint4*)((char*)d_ws + 256);  // 64 lanes * 18 uint4 = 18 KB

    cppn_pack<<<1, 64, 0, stream>>>(W1, b1, W2, b2, W3, b3, mm, fr);
    cppn_main<<<NBLK, 256, 0, stream>>>(x, b3, fr, out, mm);
    cppn_norm<<<(NPIX * NO / 4) / 256, 256, 0, stream>>>((float4*)out, mm);
}

// Round 5
// 58.322 us; speedup vs baseline: 5.0714x; 1.2812x over previous
//
#include <hip/hip_runtime.h>
#include <math.h>

#define NPIX 1048576
#define HH 64
#define NO 3
#define NBLK 2048
#define ITER 8     // NBLK * 4 waves * ITER * 16 px = 1048576
#define K2C 2.8853900817779268f  // 2*log2(e)

typedef float f32x4 __attribute__((ext_vector_type(4)));
typedef __bf16 bf16x8 __attribute__((ext_vector_type(8)));
typedef __bf16 bf16x2 __attribute__((ext_vector_type(2)));

union BF8 { __bf16 h[8]; bf16x8 v; uint4 u4; };
union PK2 { bf16x2 h; unsigned u; };
union F4U { float f[4]; uint4 u; };

#define MFMA16(a, b, c) __builtin_amdgcn_mfma_f32_16x16x32_bf16((a), (b), (c), 0, 0, 0)

// t pre-scaled: t = 2*log2e*x (+ folded bias). tanh(x) = 1 - 2/(exp2(t)+1)
__device__ __forceinline__ float tanh_t(float t) {
    float e = __builtin_amdgcn_exp2f(t);
    float r = __builtin_amdgcn_rcpf(e + 1.0f);
    return fmaf(-2.0f, r, 1.0f);
}

// k-slot -> physical h index permutation: lane (G,q) holds C rows {16m+4G+r}
// and owns B-frag k-slots {8G+j} (Bf0) and {32+8G+j} (Bf1). Bijection:
__device__ __forceinline__ int hsel(int k) {
    const int G = (k & 31) >> 3, j = k & 7;
    return ((k >= 32) ? 32 : 0) + ((j >= 4) ? 16 : 0) + 4 * G + (j & 3);
}

// ---- pre-pack, 4-wave parallel: per-lane MFMA A-fragments + scaled b2 ----
// K2C folded into A1/A2 so the tanh pre-scale multiply disappears from main.
// layout per lane (18 uint4): [0..3]=A1, [4..11]=A2[s][m], [12..13]=A3, [14..17]=K2*b2
__global__ __launch_bounds__(256) void cppn_pack(
    const float* __restrict__ W1, const float* __restrict__ b1,
    const float* __restrict__ W2, const float* __restrict__ b2,
    const float* __restrict__ W3, const float* __restrict__ b3,
    uint4* __restrict__ fr)
{
    const int t = threadIdx.x, w = t >> 6, l = t & 63, g = l >> 4, q = l & 15;
    uint4* o = fr + l * 18;

    if (w == 0) {
        // L1: A[row=h][k] = K2 * W1aug[k][h]; k<4 -> W1, k==4 -> b1 (bias fold)
        #pragma unroll
        for (int m = 0; m < 4; ++m) {
            BF8 tt;
            #pragma unroll
            for (int j = 0; j < 8; ++j) {
                const int k = g * 8 + j;
                float v = 0.0f;
                if (k < 4) v = W1[k * HH + m * 16 + q];
                else if (k == 4) v = b1[m * 16 + q];
                tt.h[j] = (__bf16)(K2C * v);
            }
            o[m] = tt.u4;
        }
    } else if (w == 1 || w == 2) {
        // L2: A[row=h2][k] = K2 * W2[hsel(k)][h2]  (k-permuted; B comes free from C1 regs)
        const int s = w - 1;
        #pragma unroll
        for (int m = 0; m < 4; ++m) {
            BF8 tt;
            #pragma unroll
            for (int j = 0; j < 8; ++j)
                tt.h[j] = (__bf16)(K2C * W2[hsel(s * 32 + g * 8 + j) * HH + m * 16 + q]);
            o[4 + s * 4 + m] = tt.u4;
        }
    } else {
        // L3: A[row=o][k] = W3[hsel(k)][o] (unscaled), rows 3..15 zero
        #pragma unroll
        for (int s = 0; s < 2; ++s) {
            BF8 tt;
            #pragma unroll
            for (int j = 0; j < 8; ++j)
                tt.h[j] = (q < NO) ? (__bf16)W3[hsel(s * 32 + g * 8 + j) * NO + q] : (__bf16)0.0f;
            o[12 + s] = tt.u4;
        }
        // pre-scaled L2 bias slice: K2 * b2[m*16 + g*4 + r]
        #pragma unroll
        for (int m = 0; m < 4; ++m) {
            F4U tt;
            #pragma unroll
            for (int r = 0; r < 4; ++r) tt.f[r] = K2C * b2[m * 16 + g * 4 + r];
            o[14 + m] = tt.u;
        }
    }
}

__global__ __launch_bounds__(256) void cppn_main(
    const float* __restrict__ x,
    const float* __restrict__ b3,
    const uint4* __restrict__ fr,
    float* __restrict__ out,
    float* __restrict__ pmin, float* __restrict__ pmax)
{
    __shared__ float rmin[4], rmax[4];

    const int t = threadIdx.x;
    const int w = t >> 6;
    const int l = t & 63;
    const int g = l >> 4;
    const int q = l & 15;

    // ---- load prebuilt fragments (18 dwordx4, L2-hit) ----
    const uint4* fo = fr + l * 18;
    bf16x8 A1[4], A2[2][4], A3[2];
    #pragma unroll
    for (int m = 0; m < 4; ++m) { BF8 u; u.u4 = fo[m]; A1[m] = u.v; }
    #pragma unroll
    for (int s = 0; s < 2; ++s)
        #pragma unroll
        for (int m = 0; m < 4; ++m) { BF8 u; u.u4 = fo[4 + s * 4 + m]; A2[s][m] = u.v; }
    #pragma unroll
    for (int s = 0; s < 2; ++s) { BF8 u; u.u4 = fo[12 + s]; A3[s] = u.v; }
    float Kb[16];
    #pragma unroll
    for (int m = 0; m < 4; ++m) {
        F4U u; u.u = fo[14 + m];
        #pragma unroll
        for (int r = 0; r < 4; ++r) Kb[m * 4 + r] = u.f[r];
    }
    const float b30 = b3[0], b31 = b3[1], b32 = b3[2];

    const f32x4 z = {0.0f, 0.0f, 0.0f, 0.0f};
    float vmin = INFINITY, vmax = -INFINITY;

    const int pbase = ((blockIdx.x * 4 + w) * ITER) * 16 + q;  // pixel index, it steps +16
    const float4* x4 = reinterpret_cast<const float4*>(x);

    float4 cur = x4[pbase];

    #pragma unroll 2
    for (int it = 0; it < ITER; ++it) {
        // prefetch next iteration's x before the long compute body
        const int itn = (it + 1 < ITER) ? it + 1 : it;
        const float4 nxt = x4[pbase + itn * 16];

        // B1 frag: xaug^T[k][px]; only g==0 lanes carry {x0..x3, 1}
        BF8 bx;
        bx.u4 = uint4{0, 0, 0, 0};
        if (g == 0) {
            PK2 p01, p23;
            p01.h = bf16x2{(__bf16)cur.x, (__bf16)cur.y};
            p23.h = bf16x2{(__bf16)cur.z, (__bf16)cur.w};
            bx.u4.x = p01.u;
            bx.u4.y = p23.u;
            bx.u4.z = 0x3F80u;  // {1.0bf16, 0} bias lane k=4
        }

        // ---- layer 1 (A1 pre-scaled by K2) ----
        f32x4 c1[4];
        #pragma unroll
        for (int m = 0; m < 4; ++m) c1[m] = MFMA16(A1[m], bx.v, z);

        unsigned pkx[4], pky[4];
        #pragma unroll
        for (int m = 0; m < 4; ++m) {
            const float t0 = tanh_t(c1[m][0]);
            const float t1 = tanh_t(c1[m][1]);
            const float t2 = tanh_t(c1[m][2]);
            const float t3 = tanh_t(c1[m][3]);
            PK2 lo, hi;
            lo.h = bf16x2{(__bf16)t0, (__bf16)t1};
            hi.h = bf16x2{(__bf16)t2, (__bf16)t3};
            pkx[m] = lo.u; pky[m] = hi.u;
        }
        BF8 Bf0, Bf1;
        Bf0.u4 = uint4{pkx[0], pky[0], pkx[1], pky[1]};
        Bf1.u4 = uint4{pkx[2], pky[2], pkx[3], pky[3]};

        // ---- layer 2 (A2 pre-scaled by K2; bias add pre-scaled) ----
        f32x4 c2[4];
        #pragma unroll
        for (int m = 0; m < 4; ++m) {
            c2[m] = MFMA16(A2[0][m], Bf0.v, z);
            c2[m] = MFMA16(A2[1][m], Bf1.v, c2[m]);
        }
        #pragma unroll
        for (int m = 0; m < 4; ++m) {
            const float t0 = tanh_t(c2[m][0] + Kb[m * 4 + 0]);
            const float t1 = tanh_t(c2[m][1] + Kb[m * 4 + 1]);
            const float t2 = tanh_t(c2[m][2] + Kb[m * 4 + 2]);
            const float t3 = tanh_t(c2[m][3] + Kb[m * 4 + 3]);
            PK2 lo, hi;
            lo.h = bf16x2{(__bf16)t0, (__bf16)t1};
            hi.h = bf16x2{(__bf16)t2, (__bf16)t3};
            pkx[m] = lo.u; pky[m] = hi.u;
        }
        BF8 Bg0, Bg1;
        Bg0.u4 = uint4{pkx[0], pky[0], pkx[1], pky[1]};
        Bg1.u4 = uint4{pkx[2], pky[2], pkx[3], pky[3]};

        // ---- layer 3 ----
        f32x4 c3 = MFMA16(A3[0], Bg0.v, z);
        c3 = MFMA16(A3[1], Bg1.v, c3);

        if (g == 0) {
            const int pxg = pbase + it * 16;
            const float o0 = c3[0] + b30;
            const float o1 = c3[1] + b31;
            const float o2 = c3[2] + b32;
            out[0 * NPIX + pxg] = o0;
            out[1 * NPIX + pxg] = o1;
            out[2 * NPIX + pxg] = o2;
            vmin = fminf(vmin, fminf(fminf(o0, o1), o2));
            vmax = fmaxf(vmax, fmaxf(fmaxf(o0, o1), o2));
        }
        cur = nxt;
    }

    // per-block min/max -> partials (no global atomics, no tail convoy)
    #pragma unroll
    for (int off = 32; off > 0; off >>= 1) {
        vmin = fminf(vmin, __shfl_down(vmin, off));
        vmax = fmaxf(vmax, __shfl_down(vmax, off));
    }
    if (l == 0) { rmin[w] = vmin; rmax[w] = vmax; }
    __syncthreads();
    if (t == 0) {
        pmin[blockIdx.x] = fminf(fminf(rmin[0], rmin[1]), fminf(rmin[2], rmin[3]));
        pmax[blockIdx.x] = fmaxf(fmaxf(rmax[0], rmax[1]), fmaxf(rmax[2], rmax[3]));
    }
}

// fold 2048 per-block partials into mm[0]=min, mm[1]=max
__global__ __launch_bounds__(256) void cppn_reduce(
    const float* __restrict__ pmin, const float* __restrict__ pmax,
    float* __restrict__ mm)
{
    __shared__ float rmin[4], rmax[4];
    const int t = threadIdx.x, w = t >> 6, l = t & 63;
    float mn = INFINITY, mx = -INFINITY;
    for (int i = t; i < NBLK; i += 256) {
        mn = fminf(mn, pmin[i]);
        mx = fmaxf(mx, pmax[i]);
    }
    #pragma unroll
    for (int off = 32; off > 0; off >>= 1) {
        mn = fminf(mn, __shfl_down(mn, off));
        mx = fmaxf(mx, __shfl_down(mx, off));
    }
    if (l == 0) { rmin[w] = mn; rmax[w] = mx; }
    __syncthreads();
    if (t == 0) {
        mm[0] = fminf(fminf(rmin[0], rmin[1]), fminf(rmin[2], rmin[3]));
        mm[1] = fmaxf(fmaxf(rmax[0], rmax[1]), fmaxf(rmax[2], rmax[3]));
    }
}

__global__ __launch_bounds__(256) void cppn_norm(float4* __restrict__ out,
                                                 const float* __restrict__ mm)
{
    const float mn = mm[0];
    const float mx = mm[1];
    const float inv = __fdividef(1.0f, mx - mn);
    const int i = blockIdx.x * 256 + threadIdx.x;
    float4 v = out[i];
    v.x = fminf(fmaxf((v.x - mn) * inv, 0.0f), 1.0f);
    v.y = fminf(fmaxf((v.y - mn) * inv, 0.0f), 1.0f);
    v.z = fminf(fmaxf((v.z - mn) * inv, 0.0f), 1.0f);
    v.w = fminf(fmaxf((v.w - mn) * inv, 0.0f), 1.0f);
    out[i] = v;
}

extern "C" void kernel_launch(void* const* d_in, const int* in_sizes, int n_in,
                              void* d_out, int out_size, void* d_ws, size_t ws_size,
                              hipStream_t stream) {
    const float* x  = (const float*)d_in[0];
    const float* W1 = (const float*)d_in[1];
    const float* b1 = (const float*)d_in[2];
    const float* W2 = (const float*)d_in[3];
    const float* b2 = (const float*)d_in[4];
    const float* W3 = (const float*)d_in[5];
    const float* b3 = (const float*)d_in[6];
    float* out = (float*)d_out;

    float* mm   = (float*)d_ws;                          // 2 floats
    float* pmin = (float*)((char*)d_ws + 1024);          // 2048 floats
    float* pmax = (float*)((char*)d_ws + 1024 + 8192);   // 2048 floats
    uint4* fr   = (uint4*)((char*)d_ws + 32768);         // 64 lanes * 18 uint4 = 18 KB

    cppn_pack<<<1, 256, 0, stream>>>(W1, b1, W2, b2, W3, b3, fr);
    cppn_main<<<NBLK, 256, 0, stream>>>(x, b3, fr, out, pmin, pmax);
    cppn_reduce<<<1, 256, 0, stream>>>(pmin, pmax, mm);
    cppn_norm<<<(NPIX * NO / 4) / 256, 256, 0, stream>>>((float4*)out, mm);
}